// Round 5
// baseline (421.693 us; speedup 1.0000x reference)
//
#include <hip/hip_runtime.h>

#define E_TOTAL 1000000
#define NN 50000
#define NB_SCAN ((NN + 255) / 256)

typedef __attribute__((ext_vector_type(8))) short bf16x8;
typedef __attribute__((ext_vector_type(8))) __bf16 bfv8;
typedef __attribute__((ext_vector_type(4))) float f32x4;
typedef __attribute__((ext_vector_type(8))) unsigned short u16x8;

__device__ __forceinline__ float bf2f(unsigned short u) {
  unsigned int x = ((unsigned int)u) << 16;
  return __builtin_bit_cast(float, x);
}

__device__ __forceinline__ unsigned short f2bf(float v) {
  __bf16 b = (__bf16)v;
  return __builtin_bit_cast(unsigned short, b);
}

__device__ __forceinline__ bf16x8 pack8(float4 u, float4 v) {
  bfv8 f;
  f[0] = (__bf16)u.x; f[1] = (__bf16)u.y; f[2] = (__bf16)u.z; f[3] = (__bf16)u.w;
  f[4] = (__bf16)v.x; f[5] = (__bf16)v.y; f[6] = (__bf16)v.z; f[7] = (__bf16)v.w;
  return __builtin_bit_cast(bf16x8, f);
}

__device__ __forceinline__ bf16x8 cvt8(const float* __restrict__ p) {
  return pack8(*reinterpret_cast<const float4*>(p), *reinterpret_cast<const float4*>(p + 4));
}

__device__ __forceinline__ bf16x8 cvt8s(const float* __restrict__ p, float s) {
  const float4 v0 = *reinterpret_cast<const float4*>(p);
  const float4 v1 = *reinterpret_cast<const float4*>(p + 4);
  bfv8 f;
  f[0] = (__bf16)(v0.x * s); f[1] = (__bf16)(v0.y * s); f[2] = (__bf16)(v0.z * s); f[3] = (__bf16)(v0.w * s);
  f[4] = (__bf16)(v1.x * s); f[5] = (__bf16)(v1.y * s); f[6] = (__bf16)(v1.z * s); f[7] = (__bf16)(v1.w * s);
  return __builtin_bit_cast(bf16x8, f);
}

// ---------------- CSR build (counting sort of edges by destination) ------

__global__ void count_kernel(const int* __restrict__ ei, float* __restrict__ counts) {
  int i = blockIdx.x * blockDim.x + threadIdx.x;
  if (i < E_TOTAL) atomicAdd(counts + ei[E_TOTAL + i], 1.0f);
}

__global__ void hist_kernel(const int* __restrict__ ei, int* __restrict__ cnt) {
  int i = blockIdx.x * blockDim.x + threadIdx.x;
  if (i < E_TOTAL) atomicAdd(cnt + ei[E_TOTAL + i], 1);
}

__global__ void scan_block_kernel(const int* __restrict__ cnt, int* __restrict__ offs,
                                  int* __restrict__ btot) {
  __shared__ int s[256];
  const int tid = threadIdx.x;
  const int i = blockIdx.x * 256 + tid;
  int v = (i < NN) ? cnt[i] : 0;
  s[tid] = v;
  __syncthreads();
#pragma unroll
  for (int d = 1; d < 256; d <<= 1) {
    int t = (tid >= d) ? s[tid - d] : 0;
    __syncthreads();
    s[tid] += t;
    __syncthreads();
  }
  int incl = s[tid];
  if (i < NN) offs[i] = incl - v;  // exclusive within block
  if (tid == 255) btot[blockIdx.x] = incl;
}

__global__ void scan_top_kernel(int* __restrict__ btot) {
  __shared__ int s[256];
  const int tid = threadIdx.x;
  int v = (tid < NB_SCAN) ? btot[tid] : 0;
  s[tid] = v;
  __syncthreads();
#pragma unroll
  for (int d = 1; d < 256; d <<= 1) {
    int t = (tid >= d) ? s[tid - d] : 0;
    __syncthreads();
    s[tid] += t;
    __syncthreads();
  }
  if (tid < NB_SCAN) btot[tid] = s[tid] - v;  // exclusive
}

__global__ void scan_add_kernel(int* __restrict__ offs, const int* __restrict__ btot,
                                int* __restrict__ run) {
  const int i = blockIdx.x * 256 + threadIdx.x;
  if (i < NN) {
    int o = offs[i] + btot[i >> 8];
    offs[i] = o;
    run[i] = o;
  }
  if (i == 0) offs[NN] = E_TOTAL;
}

// perm[e] = CSR slot of edge e (destination-sorted position)
__global__ void perm_kernel(const int* __restrict__ ei, int* __restrict__ run,
                            int* __restrict__ perm) {
  int i = blockIdx.x * blockDim.x + threadIdx.x;
  if (i < E_TOTAL) perm[i] = atomicAdd(run + ei[E_TOTAL + i], 1);
}

// ---------------- edge MLP ------------------------------------------------
// 512-thread blocks: 8 waves share ONE 24 KiB weight-fragment LDS copy
// (amortized: 43 KiB/block -> 3 blocks/CU -> 24 waves/CU occupancy cap,
// vs 16 at 256 threads). launch_bounds(512,6) pins VGPR <= 85.
// MODE 0: atomic scatter (fallback). MODE 1: write bf16 row to CSR slot.
template <int MODE>
__global__ __launch_bounds__(512, 6) void edge_kernel(
    const float* __restrict__ x, const int* __restrict__ ei,
    const float* __restrict__ ea, const float* __restrict__ W1,
    const float* __restrict__ b1, const float* __restrict__ W2,
    const float* __restrict__ b2, float* __restrict__ sums,
    unsigned short* __restrict__ hbuf, const int* __restrict__ perm) {
  __shared__ unsigned short wlds[24 * 512];       // 16 W1 + 8 W2 frag-tiles
  __shared__ unsigned short h_lds[8][16 * 72];    // per-wave transpose slab
  const int tid = threadIdx.x;
  const int w = tid >> 6, l = tid & 63;
  const int c = l & 15, g = l >> 4;

  // Stage MFMA B-fragments: frag-tile ft=s*4+t, lane ll, elem e holds
  // W[(s*32 + (ll>>4)*8 + e)][t*16 + (ll&15)] so each lane reads 16B linear.
  for (int idx = tid; idx < 16 * 512; idx += 512) {
    const int e = idx & 7, ll = (idx >> 3) & 63, ft = idx >> 9;
    const int s = ft >> 2, t = ft & 3;
    wlds[idx] = f2bf(W1[(s * 32 + (ll >> 4) * 8 + e) * 64 + t * 16 + (ll & 15)]);
  }
  for (int idx = tid; idx < 8 * 512; idx += 512) {
    const int e = idx & 7, ll = (idx >> 3) & 63, ft = idx >> 9;
    const int s = ft >> 2, t = ft & 3;
    wlds[16 * 512 + idx] = f2bf(W2[(s * 32 + (ll >> 4) * 8 + e) * 64 + t * 16 + (ll & 15)]);
  }
  __syncthreads();

  const int ebase0 = blockIdx.x * 512 + w * 64;
  if (ebase0 >= E_TOTAL) return;  // after the only __syncthreads

  float b1v[4], b2v[4];
#pragma unroll
  for (int t = 0; t < 4; ++t) {
    b1v[t] = b1[t * 16 + c];
    b2v[t] = b2[t * 16 + c];
  }
  unsigned short* hl = h_lds[w];

  // ---- prologue: tile 0 loads ----
  int idxc = ei[ebase0 + c];
  int pvc = (MODE == 1) ? perm[ebase0 + c] : 0;
  const float* xp0 = x + (long)idxc * 64 + g * 8;
  const float* ap0 = ea + (long)(ebase0 + c) * 64 + g * 8;
  float4 xc0 = *reinterpret_cast<const float4*>(xp0);
  float4 xc1 = *reinterpret_cast<const float4*>(xp0 + 4);
  float4 xc2 = *reinterpret_cast<const float4*>(xp0 + 32);
  float4 xc3 = *reinterpret_cast<const float4*>(xp0 + 36);
  float4 ac0 = *reinterpret_cast<const float4*>(ap0);
  float4 ac1 = *reinterpret_cast<const float4*>(ap0 + 4);
  float4 ac2 = *reinterpret_cast<const float4*>(ap0 + 32);
  float4 ac3 = *reinterpret_cast<const float4*>(ap0 + 36);

#pragma unroll 1
  for (int it = 0; it < 4; ++it) {
    const int ebc = ebase0 + it * 16;
    const bool hasnext = (it < 3);

    // current A fragments (rows = 16 edges, k = 128 feat)
    bf16x8 a0 = pack8(xc0, xc1);
    bf16x8 a1 = pack8(xc2, xc3);
    bf16x8 a2 = pack8(ac0, ac1);
    bf16x8 a3 = pack8(ac2, ac3);

    // prefetch next tile: indices + ea (independent of anything current)
    int idxn = 0, pvn = 0;
    float4 an0, an1, an2, an3, xn0, xn1, xn2, xn3;
    if (hasnext) {
      idxn = ei[ebc + 16 + c];
      if (MODE == 1) pvn = perm[ebc + 16 + c];
      const float* apn = ea + (long)(ebc + 16 + c) * 64 + g * 8;
      an0 = *reinterpret_cast<const float4*>(apn);
      an1 = *reinterpret_cast<const float4*>(apn + 4);
      an2 = *reinterpret_cast<const float4*>(apn + 32);
      an3 = *reinterpret_cast<const float4*>(apn + 36);
    }

    // layer 1: 16 MFMAs, B-frags streamed from LDS
    f32x4 acc[4];
#pragma unroll
    for (int t = 0; t < 4; ++t) acc[t] = (f32x4){0.f, 0.f, 0.f, 0.f};
#pragma unroll
    for (int t = 0; t < 4; ++t) {
      bf16x8 wf0 = *reinterpret_cast<const bf16x8*>(wlds + ((0 * 4 + t) * 64 + l) * 8);
      bf16x8 wf1 = *reinterpret_cast<const bf16x8*>(wlds + ((1 * 4 + t) * 64 + l) * 8);
      bf16x8 wf2 = *reinterpret_cast<const bf16x8*>(wlds + ((2 * 4 + t) * 64 + l) * 8);
      bf16x8 wf3 = *reinterpret_cast<const bf16x8*>(wlds + ((3 * 4 + t) * 64 + l) * 8);
      acc[t] = __builtin_amdgcn_mfma_f32_16x16x32_bf16(a0, wf0, acc[t], 0, 0, 0);
      acc[t] = __builtin_amdgcn_mfma_f32_16x16x32_bf16(a1, wf1, acc[t], 0, 0, 0);
      acc[t] = __builtin_amdgcn_mfma_f32_16x16x32_bf16(a2, wf2, acc[t], 0, 0, 0);
      acc[t] = __builtin_amdgcn_mfma_f32_16x16x32_bf16(a3, wf3, acc[t], 0, 0, 0);
    }

    // prefetch next tile's x gather (idxn latency was hidden by the MFMAs)
    if (hasnext) {
      const float* xpn = x + (long)idxn * 64 + g * 8;
      xn0 = *reinterpret_cast<const float4*>(xpn);
      xn1 = *reinterpret_cast<const float4*>(xpn + 4);
      xn2 = *reinterpret_cast<const float4*>(xpn + 32);
      xn3 = *reinterpret_cast<const float4*>(xpn + 36);
    }

    // bias + ReLU -> LDS transpose slab
#pragma unroll
    for (int t = 0; t < 4; ++t)
#pragma unroll
      for (int r = 0; r < 4; ++r)
        hl[(g * 4 + r) * 72 + t * 16 + c] = f2bf(fmaxf(acc[t][r] + b1v[t], 0.f));
    __builtin_amdgcn_wave_barrier();
    bf16x8 h0 = *reinterpret_cast<const bf16x8*>(hl + c * 72 + g * 8);
    bf16x8 h1 = *reinterpret_cast<const bf16x8*>(hl + c * 72 + 32 + g * 8);

    // layer 2: 8 MFMAs
    f32x4 o[4];
#pragma unroll
    for (int t = 0; t < 4; ++t) o[t] = (f32x4){0.f, 0.f, 0.f, 0.f};
#pragma unroll
    for (int t = 0; t < 4; ++t) {
      bf16x8 wf0 = *reinterpret_cast<const bf16x8*>(wlds + 16 * 512 + ((0 * 4 + t) * 64 + l) * 8);
      bf16x8 wf1 = *reinterpret_cast<const bf16x8*>(wlds + 16 * 512 + ((1 * 4 + t) * 64 + l) * 8);
      o[t] = __builtin_amdgcn_mfma_f32_16x16x32_bf16(h0, wf0, o[t], 0, 0, 0);
      o[t] = __builtin_amdgcn_mfma_f32_16x16x32_bf16(h1, wf1, o[t], 0, 0, 0);
    }
    __builtin_amdgcn_wave_barrier();

    if (MODE == 0) {
#pragma unroll
      for (int r = 0; r < 4; ++r) {
        const int node = ei[E_TOTAL + ebc + g * 4 + r];
#pragma unroll
        for (int t = 0; t < 4; ++t)
          atomicAdd(sums + (long)node * 64 + t * 16 + c, o[t][r] + b2v[t]);
      }
    } else {
      // repack D-layout -> contiguous bf16 row, store to CSR slot perm[edge]
#pragma unroll
      for (int t = 0; t < 4; ++t)
#pragma unroll
        for (int r = 0; r < 4; ++r)
          hl[(g * 4 + r) * 72 + t * 16 + c] = f2bf(o[t][r] + b2v[t]);
      __builtin_amdgcn_wave_barrier();
      {
        const int srow = l >> 2, k4 = l & 3;
        const int pos = __shfl(pvc, srow);
        const unsigned short* src = hl + srow * 72 + k4 * 16;
        unsigned short* dst = hbuf + (size_t)pos * 64 + k4 * 16;
        u16x8 v0 = *reinterpret_cast<const u16x8*>(src);
        u16x8 v1 = *reinterpret_cast<const u16x8*>(src + 8);
        *reinterpret_cast<u16x8*>(dst) = v0;
        *reinterpret_cast<u16x8*>(dst + 8) = v1;
      }
      __builtin_amdgcn_wave_barrier();
    }

    // rotate prefetched registers in
    if (hasnext) {
      xc0 = xn0; xc1 = xn1; xc2 = xn2; xc3 = xn3;
      ac0 = an0; ac1 = an1; ac2 = an2; ac3 = an3;
      pvc = pvn;
    }
  }
}

// ---------------- gather-reduce: rows destination-sorted => streaming ------
// 8 rows/iter, u16x8 (16B) per lane, 3-step shuffle reduction.
__global__ __launch_bounds__(256, 1) void reduce_kernel(
    const unsigned short* __restrict__ hbuf, const int* __restrict__ offs,
    float* __restrict__ out) {
  const int l = threadIdx.x & 63, w = threadIdx.x >> 6;
  const int n = blockIdx.x * 4 + w;
  if (n >= NN) return;  // wave-uniform
  const int start = offs[n], end = offs[n + 1];
  const int slot = l >> 3, ch8 = (l & 7) * 8;
  float acc[8];
#pragma unroll
  for (int k = 0; k < 8; ++k) acc[k] = 0.f;
  for (int j0 = start; j0 < end; j0 += 8) {
    const int j = j0 + slot;
    if (j < end) {
      u16x8 v = *reinterpret_cast<const u16x8*>(hbuf + (size_t)j * 64 + ch8);
#pragma unroll
      for (int k = 0; k < 8; ++k) acc[k] += bf2f(v[k]);
    }
  }
#pragma unroll
  for (int k = 0; k < 8; ++k) {
    float v = acc[k];
    v += __shfl_xor(v, 8);
    v += __shfl_xor(v, 16);
    v += __shfl_xor(v, 32);
    acc[k] = v;
  }
  if (l < 8) {
    const float inv = 1.0f / fmaxf((float)(end - start), 1.0f);
    float* op = out + (size_t)n * 64 + l * 8;
    float4 r0 = {acc[0] * inv, acc[1] * inv, acc[2] * inv, acc[3] * inv};
    float4 r1 = {acc[4] * inv, acc[5] * inv, acc[6] * inv, acc[7] * inv};
    *reinterpret_cast<float4*>(op) = r0;
    *reinterpret_cast<float4*>(op + 4) = r1;
  }
}

// ---------------- node MLP -------------------------------------------------
template <bool WITH_INV>
__global__ __launch_bounds__(256, 1) void node_kernel(
    const float* __restrict__ x, const int* __restrict__ batch,
    const float* __restrict__ u, const float* __restrict__ W3,
    const float* __restrict__ b3, const float* __restrict__ W4,
    const float* __restrict__ b4, const float* __restrict__ counts,
    float* __restrict__ out) {
  __shared__ unsigned short h_lds[4][16 * 72];
  const int tid = threadIdx.x;
  const int w = tid >> 6, l = tid & 63;
  const int c = l & 15, g = l >> 4;

  bf16x8 w3f[6][4];
#pragma unroll
  for (int s = 0; s < 6; ++s)
#pragma unroll
    for (int t = 0; t < 4; ++t) {
      const float* wp = W3 + (s * 32 + g * 8) * 64 + t * 16 + c;
      bfv8 f;
#pragma unroll
      for (int e = 0; e < 8; ++e) f[e] = (__bf16)wp[e * 64];
      w3f[s][t] = __builtin_bit_cast(bf16x8, f);
    }
  bf16x8 w4f[2][4];
#pragma unroll
  for (int s = 0; s < 2; ++s)
#pragma unroll
    for (int t = 0; t < 4; ++t) {
      const float* wp = W4 + (s * 32 + g * 8) * 64 + t * 16 + c;
      bfv8 f;
#pragma unroll
      for (int e = 0; e < 8; ++e) f[e] = (__bf16)wp[e * 64];
      w4f[s][t] = __builtin_bit_cast(bf16x8, f);
    }
  float b3v[4], b4v[4];
#pragma unroll
  for (int t = 0; t < 4; ++t) {
    b3v[t] = b3[t * 16 + c];
    b4v[t] = b4[t * 16 + c];
  }

  unsigned short* hl = h_lds[w];
  const int nbase0 = blockIdx.x * 256 + w * 64;
#pragma unroll 1
  for (int it = 0; it < 4; ++it) {
    const int nb = nbase0 + it * 16;
    if (nb >= NN) break;  // wave-uniform
    const int my_n = nb + c;
    const float* xp = x + (long)my_n * 64 + g * 8;
    const float* sp = out + (long)my_n * 64 + g * 8;
    const float* up = u + (long)batch[my_n] * 64 + g * 8;
    bf16x8 a0 = cvt8(xp);
    bf16x8 a1 = cvt8(xp + 32);
    bf16x8 a2, a3;
    if (WITH_INV) {
      const float inv = 1.0f / fmaxf(counts[my_n], 1.0f);
      a2 = cvt8s(sp, inv);
      a3 = cvt8s(sp + 32, inv);
    } else {
      a2 = cvt8(sp);
      a3 = cvt8(sp + 32);
    }
    bf16x8 a4 = cvt8(up);
    bf16x8 a5 = cvt8(up + 32);

    f32x4 acc[4];
#pragma unroll
    for (int t = 0; t < 4; ++t) acc[t] = (f32x4){0.f, 0.f, 0.f, 0.f};
#pragma unroll
    for (int t = 0; t < 4; ++t) {
      acc[t] = __builtin_amdgcn_mfma_f32_16x16x32_bf16(a0, w3f[0][t], acc[t], 0, 0, 0);
      acc[t] = __builtin_amdgcn_mfma_f32_16x16x32_bf16(a1, w3f[1][t], acc[t], 0, 0, 0);
      acc[t] = __builtin_amdgcn_mfma_f32_16x16x32_bf16(a2, w3f[2][t], acc[t], 0, 0, 0);
      acc[t] = __builtin_amdgcn_mfma_f32_16x16x32_bf16(a3, w3f[3][t], acc[t], 0, 0, 0);
      acc[t] = __builtin_amdgcn_mfma_f32_16x16x32_bf16(a4, w3f[4][t], acc[t], 0, 0, 0);
      acc[t] = __builtin_amdgcn_mfma_f32_16x16x32_bf16(a5, w3f[5][t], acc[t], 0, 0, 0);
    }
#pragma unroll
    for (int t = 0; t < 4; ++t)
#pragma unroll
      for (int r = 0; r < 4; ++r)
        hl[(g * 4 + r) * 72 + t * 16 + c] = f2bf(fmaxf(acc[t][r] + b3v[t], 0.f));
    __builtin_amdgcn_wave_barrier();
    bf16x8 h0 = *reinterpret_cast<const bf16x8*>(hl + c * 72 + g * 8);
    bf16x8 h1 = *reinterpret_cast<const bf16x8*>(hl + c * 72 + 32 + g * 8);
    f32x4 o[4];
#pragma unroll
    for (int t = 0; t < 4; ++t) o[t] = (f32x4){0.f, 0.f, 0.f, 0.f};
#pragma unroll
    for (int t = 0; t < 4; ++t) {
      o[t] = __builtin_amdgcn_mfma_f32_16x16x32_bf16(h0, w4f[0][t], o[t], 0, 0, 0);
      o[t] = __builtin_amdgcn_mfma_f32_16x16x32_bf16(h1, w4f[1][t], o[t], 0, 0, 0);
    }
    __builtin_amdgcn_wave_barrier();
#pragma unroll
    for (int r = 0; r < 4; ++r) {
      const int nrow = nb + g * 4 + r;
#pragma unroll
      for (int t = 0; t < 4; ++t)
        out[(long)nrow * 64 + t * 16 + c] = o[t][r] + b4v[t];
    }
  }
}

extern "C" void kernel_launch(void* const* d_in, const int* in_sizes, int n_in,
                              void* d_out, int out_size, void* d_ws, size_t ws_size,
                              hipStream_t stream) {
  const float* x = (const float*)d_in[0];
  const int* ei = (const int*)d_in[1];
  const float* ea = (const float*)d_in[2];
  const float* u = (const float*)d_in[3];
  const int* batch = (const int*)d_in[4];
  const float* W1 = (const float*)d_in[5];
  const float* b1 = (const float*)d_in[6];
  const float* W2 = (const float*)d_in[7];
  const float* b2 = (const float*)d_in[8];
  const float* W3 = (const float*)d_in[9];
  const float* b3 = (const float*)d_in[10];
  const float* W4 = (const float*)d_in[11];
  const float* b4 = (const float*)d_in[12];
  float* out = (float*)d_out;

  // workspace layout for the CSR (split) path
  const size_t HB_OFF = 0;                    // 1M x 64 bf16   = 128,000,000 B
  const size_t PERM_OFF = 128000000;          // 1M int         =   4,000,000 B
  const size_t OFFS_OFF = 132000000;          // 50001 int
  const size_t RUN_OFF = 132400000;           // 50000 int (also histogram)
  const size_t BTOT_OFF = 132800000;          // NB_SCAN int
  const size_t NEED = 132900000;

  const int egrid = (E_TOTAL + 255) / 256;
  const int egrid512 = (E_TOTAL + 511) / 512;
  const int ngrid = (NN + 255) / 256;

  if (ws_size >= NEED) {
    unsigned short* hbuf = (unsigned short*)((char*)d_ws + HB_OFF);
    int* perm = (int*)((char*)d_ws + PERM_OFF);
    int* offs = (int*)((char*)d_ws + OFFS_OFF);
    int* run = (int*)((char*)d_ws + RUN_OFF);
    int* btot = (int*)((char*)d_ws + BTOT_OFF);

    hipMemsetAsync(run, 0, (size_t)NN * sizeof(int), stream);
    hist_kernel<<<egrid, 256, 0, stream>>>(ei, run);
    scan_block_kernel<<<NB_SCAN, 256, 0, stream>>>(run, offs, btot);
    scan_top_kernel<<<1, 256, 0, stream>>>(btot);
    scan_add_kernel<<<NB_SCAN, 256, 0, stream>>>(offs, btot, run);
    perm_kernel<<<egrid, 256, 0, stream>>>(ei, run, perm);
    edge_kernel<1><<<egrid512, 512, 0, stream>>>(x, ei, ea, W1, b1, W2, b2, nullptr, hbuf, perm);
    reduce_kernel<<<(NN + 3) / 4, 256, 0, stream>>>(hbuf, offs, out);
    node_kernel<false><<<ngrid, 256, 0, stream>>>(x, batch, u, W3, b3, W4, b4, nullptr, out);
  } else {
    // fallback: atomic path
    float* counts = (float*)d_ws;
    hipMemsetAsync(out, 0, (size_t)NN * 64 * sizeof(float), stream);
    hipMemsetAsync(counts, 0, (size_t)NN * sizeof(float), stream);
    count_kernel<<<egrid, 256, 0, stream>>>(ei, counts);
    edge_kernel<0><<<egrid512, 512, 0, stream>>>(x, ei, ea, W1, b1, W2, b2, out, nullptr, nullptr);
    node_kernel<true><<<ngrid, 256, 0, stream>>>(x, batch, u, W3, b3, W4, b4, counts, out);
  }
}

// Round 6
// 228.032 us; speedup vs baseline: 1.8493x; 1.8493x over previous
//
#include <hip/hip_runtime.h>

#define E_TOTAL 1000000
#define NN 50000
#define NB_SCAN ((NN + 255) / 256)

typedef __attribute__((ext_vector_type(8))) short bf16x8;
typedef __attribute__((ext_vector_type(8))) __bf16 bfv8;
typedef __attribute__((ext_vector_type(4))) float f32x4;
typedef __attribute__((ext_vector_type(8))) unsigned short u16x8;

__device__ __forceinline__ float bf2f(unsigned short u) {
  unsigned int x = ((unsigned int)u) << 16;
  return __builtin_bit_cast(float, x);
}

__device__ __forceinline__ unsigned short f2bf(float v) {
  __bf16 b = (__bf16)v;
  return __builtin_bit_cast(unsigned short, b);
}

__device__ __forceinline__ bf16x8 pack8(float4 u, float4 v) {
  bfv8 f;
  f[0] = (__bf16)u.x; f[1] = (__bf16)u.y; f[2] = (__bf16)u.z; f[3] = (__bf16)u.w;
  f[4] = (__bf16)v.x; f[5] = (__bf16)v.y; f[6] = (__bf16)v.z; f[7] = (__bf16)v.w;
  return __builtin_bit_cast(bf16x8, f);
}

__device__ __forceinline__ bf16x8 cvt8(const float* __restrict__ p) {
  return pack8(*reinterpret_cast<const float4*>(p), *reinterpret_cast<const float4*>(p + 4));
}

__device__ __forceinline__ bf16x8 cvt8s(const float* __restrict__ p, float s) {
  const float4 v0 = *reinterpret_cast<const float4*>(p);
  const float4 v1 = *reinterpret_cast<const float4*>(p + 4);
  bfv8 f;
  f[0] = (__bf16)(v0.x * s); f[1] = (__bf16)(v0.y * s); f[2] = (__bf16)(v0.z * s); f[3] = (__bf16)(v0.w * s);
  f[4] = (__bf16)(v1.x * s); f[5] = (__bf16)(v1.y * s); f[6] = (__bf16)(v1.z * s); f[7] = (__bf16)(v1.w * s);
  return __builtin_bit_cast(bf16x8, f);
}

// ---------------- CSR build -----------------------------------------------

__global__ void count_kernel(const int* __restrict__ ei, float* __restrict__ counts) {
  int i = blockIdx.x * blockDim.x + threadIdx.x;
  if (i < E_TOTAL) atomicAdd(counts + ei[E_TOTAL + i], 1.0f);
}

__global__ void hist_kernel(const int* __restrict__ ei, int* __restrict__ cnt) {
  int i = blockIdx.x * blockDim.x + threadIdx.x;
  if (i < E_TOTAL) atomicAdd(cnt + ei[E_TOTAL + i], 1);
}

__global__ void scan_block_kernel(const int* __restrict__ cnt, int* __restrict__ offs,
                                  int* __restrict__ btot) {
  __shared__ int s[256];
  const int tid = threadIdx.x;
  const int i = blockIdx.x * 256 + tid;
  int v = (i < NN) ? cnt[i] : 0;
  s[tid] = v;
  __syncthreads();
#pragma unroll
  for (int d = 1; d < 256; d <<= 1) {
    int t = (tid >= d) ? s[tid - d] : 0;
    __syncthreads();
    s[tid] += t;
    __syncthreads();
  }
  int incl = s[tid];
  if (i < NN) offs[i] = incl - v;  // exclusive within block
  if (tid == 255) btot[blockIdx.x] = incl;
}

// folds the top-level scan: each block sums btot[0..bid-1] itself.
__global__ void scan_add_kernel(int* __restrict__ offs, const int* __restrict__ btot,
                                int* __restrict__ run) {
  __shared__ int s[256];
  const int tid = threadIdx.x, bid = blockIdx.x;
  s[tid] = (tid < bid && tid < NB_SCAN) ? btot[tid] : 0;
  __syncthreads();
#pragma unroll
  for (int d = 128; d > 0; d >>= 1) {
    if (tid < d) s[tid] += s[tid + d];
    __syncthreads();
  }
  const int base = s[0];
  const int i = bid * 256 + tid;
  if (i < NN) {
    int o = offs[i] + base;
    offs[i] = o;
    run[i] = o;
  }
  if (i == 0) offs[NN] = E_TOTAL;
}

// ---------------- edge MLP ------------------------------------------------
// 512-thread blocks: 8 waves share one 24 KiB weight-fragment LDS copy.
// NO min-waves clamp (R5's (512,6) collapsed VGPRs to 40 and spilled to
// scratch: WRITE 125->530MB). Natural ~72-80 VGPR -> 6-7 waves/SIMD; LDS
// caps at 3 blocks/CU = 24 waves/CU.
// CSR slot claimed inline: atomicAdd(run+col,1) at tile start (g==0 lanes),
// consumed at the store phase -> no perm_kernel, no perm array.
template <int MODE>
__global__ __launch_bounds__(512) void edge_kernel(
    const float* __restrict__ x, const int* __restrict__ ei,
    const float* __restrict__ ea, const float* __restrict__ W1,
    const float* __restrict__ b1, const float* __restrict__ W2,
    const float* __restrict__ b2, float* __restrict__ sums,
    unsigned short* __restrict__ hbuf, int* __restrict__ run) {
  __shared__ unsigned short wlds[24 * 512];       // 16 W1 + 8 W2 frag-tiles
  __shared__ unsigned short h_lds[8][16 * 72];    // per-wave transpose slab
  const int tid = threadIdx.x;
  const int w = tid >> 6, l = tid & 63;
  const int c = l & 15, g = l >> 4;

  for (int idx = tid; idx < 16 * 512; idx += 512) {
    const int e = idx & 7, ll = (idx >> 3) & 63, ft = idx >> 9;
    const int s = ft >> 2, t = ft & 3;
    wlds[idx] = f2bf(W1[(s * 32 + (ll >> 4) * 8 + e) * 64 + t * 16 + (ll & 15)]);
  }
  for (int idx = tid; idx < 8 * 512; idx += 512) {
    const int e = idx & 7, ll = (idx >> 3) & 63, ft = idx >> 9;
    const int s = ft >> 2, t = ft & 3;
    wlds[16 * 512 + idx] = f2bf(W2[(s * 32 + (ll >> 4) * 8 + e) * 64 + t * 16 + (ll & 15)]);
  }
  __syncthreads();

  const int ebase0 = blockIdx.x * 512 + w * 64;
  if (ebase0 >= E_TOTAL) return;  // after the only __syncthreads

  float b1v[4], b2v[4];
#pragma unroll
  for (int t = 0; t < 4; ++t) {
    b1v[t] = b1[t * 16 + c];
    b2v[t] = b2[t * 16 + c];
  }
  unsigned short* hl = h_lds[w];

  // ---- prologue: tile 0 loads ----
  int idxc = ei[ebase0 + c];
  int colc = (MODE == 1) ? ei[E_TOTAL + ebase0 + c] : 0;
  const float* xp0 = x + (long)idxc * 64 + g * 8;
  const float* ap0 = ea + (long)(ebase0 + c) * 64 + g * 8;
  float4 xc0 = *reinterpret_cast<const float4*>(xp0);
  float4 xc1 = *reinterpret_cast<const float4*>(xp0 + 4);
  float4 xc2 = *reinterpret_cast<const float4*>(xp0 + 32);
  float4 xc3 = *reinterpret_cast<const float4*>(xp0 + 36);
  float4 ac0 = *reinterpret_cast<const float4*>(ap0);
  float4 ac1 = *reinterpret_cast<const float4*>(ap0 + 4);
  float4 ac2 = *reinterpret_cast<const float4*>(ap0 + 32);
  float4 ac3 = *reinterpret_cast<const float4*>(ap0 + 36);

#pragma unroll 1
  for (int it = 0; it < 4; ++it) {
    const int ebc = ebase0 + it * 16;
    const bool hasnext = (it < 3);

    // claim CSR slot for this tile's edges (result needed only at store)
    int posc = 0;
    if (MODE == 1 && g == 0) posc = atomicAdd(run + colc, 1);

    bf16x8 a0 = pack8(xc0, xc1);
    bf16x8 a1 = pack8(xc2, xc3);
    bf16x8 a2 = pack8(ac0, ac1);
    bf16x8 a3 = pack8(ac2, ac3);

    // prefetch next tile: indices + ea
    int idxn = 0, coln = 0;
    float4 an0, an1, an2, an3, xn0, xn1, xn2, xn3;
    if (hasnext) {
      idxn = ei[ebc + 16 + c];
      if (MODE == 1) coln = ei[E_TOTAL + ebc + 16 + c];
      const float* apn = ea + (long)(ebc + 16 + c) * 64 + g * 8;
      an0 = *reinterpret_cast<const float4*>(apn);
      an1 = *reinterpret_cast<const float4*>(apn + 4);
      an2 = *reinterpret_cast<const float4*>(apn + 32);
      an3 = *reinterpret_cast<const float4*>(apn + 36);
    }

    // layer 1: 16 MFMAs, B-frags streamed from LDS
    f32x4 acc[4];
#pragma unroll
    for (int t = 0; t < 4; ++t) acc[t] = (f32x4){0.f, 0.f, 0.f, 0.f};
#pragma unroll
    for (int t = 0; t < 4; ++t) {
      bf16x8 wf0 = *reinterpret_cast<const bf16x8*>(wlds + ((0 * 4 + t) * 64 + l) * 8);
      bf16x8 wf1 = *reinterpret_cast<const bf16x8*>(wlds + ((1 * 4 + t) * 64 + l) * 8);
      bf16x8 wf2 = *reinterpret_cast<const bf16x8*>(wlds + ((2 * 4 + t) * 64 + l) * 8);
      bf16x8 wf3 = *reinterpret_cast<const bf16x8*>(wlds + ((3 * 4 + t) * 64 + l) * 8);
      acc[t] = __builtin_amdgcn_mfma_f32_16x16x32_bf16(a0, wf0, acc[t], 0, 0, 0);
      acc[t] = __builtin_amdgcn_mfma_f32_16x16x32_bf16(a1, wf1, acc[t], 0, 0, 0);
      acc[t] = __builtin_amdgcn_mfma_f32_16x16x32_bf16(a2, wf2, acc[t], 0, 0, 0);
      acc[t] = __builtin_amdgcn_mfma_f32_16x16x32_bf16(a3, wf3, acc[t], 0, 0, 0);
    }

    // prefetch next tile's x gather (idxn latency hidden by the MFMAs)
    if (hasnext) {
      const float* xpn = x + (long)idxn * 64 + g * 8;
      xn0 = *reinterpret_cast<const float4*>(xpn);
      xn1 = *reinterpret_cast<const float4*>(xpn + 4);
      xn2 = *reinterpret_cast<const float4*>(xpn + 32);
      xn3 = *reinterpret_cast<const float4*>(xpn + 36);
    }

    // bias + ReLU -> LDS transpose slab
#pragma unroll
    for (int t = 0; t < 4; ++t)
#pragma unroll
      for (int r = 0; r < 4; ++r)
        hl[(g * 4 + r) * 72 + t * 16 + c] = f2bf(fmaxf(acc[t][r] + b1v[t], 0.f));
    __builtin_amdgcn_wave_barrier();
    bf16x8 h0 = *reinterpret_cast<const bf16x8*>(hl + c * 72 + g * 8);
    bf16x8 h1 = *reinterpret_cast<const bf16x8*>(hl + c * 72 + 32 + g * 8);

    // layer 2: 8 MFMAs
    f32x4 o[4];
#pragma unroll
    for (int t = 0; t < 4; ++t) o[t] = (f32x4){0.f, 0.f, 0.f, 0.f};
#pragma unroll
    for (int t = 0; t < 4; ++t) {
      bf16x8 wf0 = *reinterpret_cast<const bf16x8*>(wlds + 16 * 512 + ((0 * 4 + t) * 64 + l) * 8);
      bf16x8 wf1 = *reinterpret_cast<const bf16x8*>(wlds + 16 * 512 + ((1 * 4 + t) * 64 + l) * 8);
      o[t] = __builtin_amdgcn_mfma_f32_16x16x32_bf16(h0, wf0, o[t], 0, 0, 0);
      o[t] = __builtin_amdgcn_mfma_f32_16x16x32_bf16(h1, wf1, o[t], 0, 0, 0);
    }
    __builtin_amdgcn_wave_barrier();

    if (MODE == 0) {
#pragma unroll
      for (int r = 0; r < 4; ++r) {
        const int node = ei[E_TOTAL + ebc + g * 4 + r];
#pragma unroll
        for (int t = 0; t < 4; ++t)
          atomicAdd(sums + (long)node * 64 + t * 16 + c, o[t][r] + b2v[t]);
      }
    } else {
      // repack D-layout -> contiguous bf16 row, store to claimed CSR slot
#pragma unroll
      for (int t = 0; t < 4; ++t)
#pragma unroll
        for (int r = 0; r < 4; ++r)
          hl[(g * 4 + r) * 72 + t * 16 + c] = f2bf(o[t][r] + b2v[t]);
      __builtin_amdgcn_wave_barrier();
      {
        const int srow = l >> 2, k4 = l & 3;
        const int pos = __shfl(posc, srow);  // lanes 0..15 hold the slots
        const unsigned short* src = hl + srow * 72 + k4 * 16;
        unsigned short* dst = hbuf + (size_t)pos * 64 + k4 * 16;
        u16x8 v0 = *reinterpret_cast<const u16x8*>(src);
        u16x8 v1 = *reinterpret_cast<const u16x8*>(src + 8);
        *reinterpret_cast<u16x8*>(dst) = v0;
        *reinterpret_cast<u16x8*>(dst + 8) = v1;
      }
      __builtin_amdgcn_wave_barrier();
    }

    if (hasnext) {
      xc0 = xn0; xc1 = xn1; xc2 = xn2; xc3 = xn3;
      ac0 = an0; ac1 = an1; ac2 = an2; ac3 = an3;
      colc = coln;
    }
  }
}

// ---------------- gather-reduce: rows destination-sorted => streaming ------
__global__ __launch_bounds__(256, 1) void reduce_kernel(
    const unsigned short* __restrict__ hbuf, const int* __restrict__ offs,
    float* __restrict__ out) {
  const int l = threadIdx.x & 63, w = threadIdx.x >> 6;
  const int n = blockIdx.x * 4 + w;
  if (n >= NN) return;  // wave-uniform
  const int start = offs[n], end = offs[n + 1];
  const int slot = l >> 3, ch8 = (l & 7) * 8;
  float acc[8];
#pragma unroll
  for (int k = 0; k < 8; ++k) acc[k] = 0.f;
  for (int j0 = start; j0 < end; j0 += 8) {
    const int j = j0 + slot;
    if (j < end) {
      u16x8 v = *reinterpret_cast<const u16x8*>(hbuf + (size_t)j * 64 + ch8);
#pragma unroll
      for (int k = 0; k < 8; ++k) acc[k] += bf2f(v[k]);
    }
  }
#pragma unroll
  for (int k = 0; k < 8; ++k) {
    float v = acc[k];
    v += __shfl_xor(v, 8);
    v += __shfl_xor(v, 16);
    v += __shfl_xor(v, 32);
    acc[k] = v;
  }
  if (l < 8) {
    const float inv = 1.0f / fmaxf((float)(end - start), 1.0f);
    float* op = out + (size_t)n * 64 + l * 8;
    float4 r0 = {acc[0] * inv, acc[1] * inv, acc[2] * inv, acc[3] * inv};
    float4 r1 = {acc[4] * inv, acc[5] * inv, acc[6] * inv, acc[7] * inv};
    *reinterpret_cast<float4*>(op) = r0;
    *reinterpret_cast<float4*>(op + 4) = r1;
  }
}

// ---------------- node MLP -------------------------------------------------
template <bool WITH_INV>
__global__ __launch_bounds__(256, 1) void node_kernel(
    const float* __restrict__ x, const int* __restrict__ batch,
    const float* __restrict__ u, const float* __restrict__ W3,
    const float* __restrict__ b3, const float* __restrict__ W4,
    const float* __restrict__ b4, const float* __restrict__ counts,
    float* __restrict__ out) {
  __shared__ unsigned short h_lds[4][16 * 72];
  const int tid = threadIdx.x;
  const int w = tid >> 6, l = tid & 63;
  const int c = l & 15, g = l >> 4;

  bf16x8 w3f[6][4];
#pragma unroll
  for (int s = 0; s < 6; ++s)
#pragma unroll
    for (int t = 0; t < 4; ++t) {
      const float* wp = W3 + (s * 32 + g * 8) * 64 + t * 16 + c;
      bfv8 f;
#pragma unroll
      for (int e = 0; e < 8; ++e) f[e] = (__bf16)wp[e * 64];
      w3f[s][t] = __builtin_bit_cast(bf16x8, f);
    }
  bf16x8 w4f[2][4];
#pragma unroll
  for (int s = 0; s < 2; ++s)
#pragma unroll
    for (int t = 0; t < 4; ++t) {
      const float* wp = W4 + (s * 32 + g * 8) * 64 + t * 16 + c;
      bfv8 f;
#pragma unroll
      for (int e = 0; e < 8; ++e) f[e] = (__bf16)wp[e * 64];
      w4f[s][t] = __builtin_bit_cast(bf16x8, f);
    }
  float b3v[4], b4v[4];
#pragma unroll
  for (int t = 0; t < 4; ++t) {
    b3v[t] = b3[t * 16 + c];
    b4v[t] = b4[t * 16 + c];
  }

  unsigned short* hl = h_lds[w];
  const int nbase0 = blockIdx.x * 256 + w * 64;
#pragma unroll 1
  for (int it = 0; it < 4; ++it) {
    const int nb = nbase0 + it * 16;
    if (nb >= NN) break;  // wave-uniform
    const int my_n = nb + c;
    const float* xp = x + (long)my_n * 64 + g * 8;
    const float* sp = out + (long)my_n * 64 + g * 8;
    const float* up = u + (long)batch[my_n] * 64 + g * 8;
    bf16x8 a0 = cvt8(xp);
    bf16x8 a1 = cvt8(xp + 32);
    bf16x8 a2, a3;
    if (WITH_INV) {
      const float inv = 1.0f / fmaxf(counts[my_n], 1.0f);
      a2 = cvt8s(sp, inv);
      a3 = cvt8s(sp + 32, inv);
    } else {
      a2 = cvt8(sp);
      a3 = cvt8(sp + 32);
    }
    bf16x8 a4 = cvt8(up);
    bf16x8 a5 = cvt8(up + 32);

    f32x4 acc[4];
#pragma unroll
    for (int t = 0; t < 4; ++t) acc[t] = (f32x4){0.f, 0.f, 0.f, 0.f};
#pragma unroll
    for (int t = 0; t < 4; ++t) {
      acc[t] = __builtin_amdgcn_mfma_f32_16x16x32_bf16(a0, w3f[0][t], acc[t], 0, 0, 0);
      acc[t] = __builtin_amdgcn_mfma_f32_16x16x32_bf16(a1, w3f[1][t], acc[t], 0, 0, 0);
      acc[t] = __builtin_amdgcn_mfma_f32_16x16x32_bf16(a2, w3f[2][t], acc[t], 0, 0, 0);
      acc[t] = __builtin_amdgcn_mfma_f32_16x16x32_bf16(a3, w3f[3][t], acc[t], 0, 0, 0);
      acc[t] = __builtin_amdgcn_mfma_f32_16x16x32_bf16(a4, w3f[4][t], acc[t], 0, 0, 0);
      acc[t] = __builtin_amdgcn_mfma_f32_16x16x32_bf16(a5, w3f[5][t], acc[t], 0, 0, 0);
    }
#pragma unroll
    for (int t = 0; t < 4; ++t)
#pragma unroll
      for (int r = 0; r < 4; ++r)
        hl[(g * 4 + r) * 72 + t * 16 + c] = f2bf(fmaxf(acc[t][r] + b3v[t], 0.f));
    __builtin_amdgcn_wave_barrier();
    bf16x8 h0 = *reinterpret_cast<const bf16x8*>(hl + c * 72 + g * 8);
    bf16x8 h1 = *reinterpret_cast<const bf16x8*>(hl + c * 72 + 32 + g * 8);
    f32x4 o[4];
#pragma unroll
    for (int t = 0; t < 4; ++t) o[t] = (f32x4){0.f, 0.f, 0.f, 0.f};
#pragma unroll
    for (int t = 0; t < 4; ++t) {
      o[t] = __builtin_amdgcn_mfma_f32_16x16x32_bf16(h0, w4f[0][t], o[t], 0, 0, 0);
      o[t] = __builtin_amdgcn_mfma_f32_16x16x32_bf16(h1, w4f[1][t], o[t], 0, 0, 0);
    }
    __builtin_amdgcn_wave_barrier();
#pragma unroll
    for (int r = 0; r < 4; ++r) {
      const int nrow = nb + g * 4 + r;
#pragma unroll
      for (int t = 0; t < 4; ++t)
        out[(long)nrow * 64 + t * 16 + c] = o[t][r] + b4v[t];
    }
  }
}

extern "C" void kernel_launch(void* const* d_in, const int* in_sizes, int n_in,
                              void* d_out, int out_size, void* d_ws, size_t ws_size,
                              hipStream_t stream) {
  const float* x = (const float*)d_in[0];
  const int* ei = (const int*)d_in[1];
  const float* ea = (const float*)d_in[2];
  const float* u = (const float*)d_in[3];
  const int* batch = (const int*)d_in[4];
  const float* W1 = (const float*)d_in[5];
  const float* b1 = (const float*)d_in[6];
  const float* W2 = (const float*)d_in[7];
  const float* b2 = (const float*)d_in[8];
  const float* W3 = (const float*)d_in[9];
  const float* b3 = (const float*)d_in[10];
  const float* W4 = (const float*)d_in[11];
  const float* b4 = (const float*)d_in[12];
  float* out = (float*)d_out;

  // workspace layout for the CSR (split) path
  const size_t HB_OFF = 0;                    // 1M x 64 bf16   = 128,000,000 B
  const size_t OFFS_OFF = 128000000;          // 50001 int
  const size_t RUN_OFF = 128400000;           // 50000 int (histogram, then cursors)
  const size_t BTOT_OFF = 128800000;          // NB_SCAN int
  const size_t NEED = 128900000;

  const int egrid = (E_TOTAL + 255) / 256;
  const int egrid512 = (E_TOTAL + 511) / 512;
  const int ngrid = (NN + 255) / 256;

  if (ws_size >= NEED) {
    unsigned short* hbuf = (unsigned short*)((char*)d_ws + HB_OFF);
    int* offs = (int*)((char*)d_ws + OFFS_OFF);
    int* run = (int*)((char*)d_ws + RUN_OFF);
    int* btot = (int*)((char*)d_ws + BTOT_OFF);

    hipMemsetAsync(run, 0, (size_t)NN * sizeof(int), stream);
    hist_kernel<<<egrid, 256, 0, stream>>>(ei, run);
    scan_block_kernel<<<NB_SCAN, 256, 0, stream>>>(run, offs, btot);
    scan_add_kernel<<<NB_SCAN, 256, 0, stream>>>(offs, btot, run);
    edge_kernel<1><<<egrid512, 512, 0, stream>>>(x, ei, ea, W1, b1, W2, b2, nullptr, hbuf, run);
    reduce_kernel<<<(NN + 3) / 4, 256, 0, stream>>>(hbuf, offs, out);
    node_kernel<false><<<ngrid, 256, 0, stream>>>(x, batch, u, W3, b3, W4, b4, nullptr, out);
  } else {
    // fallback: atomic path
    float* counts = (float*)d_ws;
    hipMemsetAsync(out, 0, (size_t)NN * 64 * sizeof(float), stream);
    hipMemsetAsync(counts, 0, (size_t)NN * sizeof(float), stream);
    count_kernel<<<egrid, 256, 0, stream>>>(ei, counts);
    edge_kernel<0><<<egrid512, 512, 0, stream>>>(x, ei, ea, W1, b1, W2, b2, out, nullptr, nullptr);
    node_kernel<true><<<ngrid, 256, 0, stream>>>(x, batch, u, W3, b3, W4, b4, counts, out);
  }
}